// Round 1
// baseline (265.410 us; speedup 1.0000x reference)
//
#include <hip/hip_runtime.h>
#include <cmath>

#define HDIM 2048
#define NEXP 64
#define TTOT 16384
#define BM   64
#define BK   32
#define NITER (HDIM / BK)   // 64
#define LDA  (BM + 4)       // 68 floats: keeps float4 reads 16B-aligned, <=2-way bank alias
#define LDB  (NEXP + 4)
#define LDS_SC (NEXP + 4)

// ---------------------------------------------------------------------------
// Main kernel: one block = 64 tokens x all 64 experts. fp32 SGEMM (no fp32
// MFMA on CDNA4) + fused bias/top-2/softmax epilogue + aux-loss partial sums.
// ---------------------------------------------------------------------------
__global__ __launch_bounds__(256) void router_main(
    const float* __restrict__ x,        // [T, H]
    const float* __restrict__ gw,       // [E, H]
    const float* __restrict__ rep,      // [E]
    const float* __restrict__ loads,    // [E]
    const float* __restrict__ counts,   // [E]
    const int*   __restrict__ total_dec,// [1]
    float* __restrict__ out_w,          // [T*2]
    float* __restrict__ out_idx,        // [T*2] (indices stored as float)
    float* __restrict__ prob_acc,       // [E] ws accum (pre-zeroed)
    float* __restrict__ gate_acc)       // [E] ws accum (pre-zeroed)
{
    __shared__ float a_s[2][BK][LDA];   // x tile, transposed: [k][token]
    __shared__ float b_s[2][BK][LDB];   // gate tile, transposed: [k][expert]
    __shared__ float sc_s[BM][LDS_SC];  // final scores
    __shared__ float bias_s[NEXP];
    __shared__ float m_s[BM], z_s[BM];
    __shared__ int   i1_s[BM], i2_s[BM];

    const int tid = threadIdx.x;
    const int tx  = tid & 15;   // expert-group 0..15 (4 experts each)
    const int ty  = tid >> 4;   // token-group  0..15 (4 tokens each)
    const int r0  = tid >> 3;   // staging row 0..31
    const int c4  = tid & 7;    // staging float4 col 0..7
    const int t0  = blockIdx.x * BM;

    // per-expert bias: BETA*rep - GAMMA*loads + EXPL_C*sqrt(log(N+1)/(counts+eps))
    // (EMA load update is identity: 0.9*l + 0.1*l = l)
    if (tid < NEXP) {
        float L = logf((float)(*total_dec) + 1.0f);
        bias_s[tid] = 0.1f * rep[tid] - 0.1f * loads[tid]
                    + 0.1f * sqrtf(L / (counts[tid] + 1e-10f));
    }

    const int H4 = HDIM / 4;
    const float4* __restrict__ x4 = reinterpret_cast<const float4*>(x) + (size_t)t0 * H4;
    const float4* __restrict__ g4 = reinterpret_cast<const float4*>(gw);

    float acc[4][4] = {};

#define STORE_TILE(BUFI, A0, A1, B0, B1) do {                                  \
        float _t0[4] = {(A0).x, (A0).y, (A0).z, (A0).w};                       \
        float _t1[4] = {(A1).x, (A1).y, (A1).z, (A1).w};                       \
        float _t2[4] = {(B0).x, (B0).y, (B0).z, (B0).w};                       \
        float _t3[4] = {(B1).x, (B1).y, (B1).z, (B1).w};                       \
        _Pragma("unroll")                                                      \
        for (int u = 0; u < 4; ++u) {                                          \
            a_s[BUFI][c4 * 4 + u][r0]      = _t0[u];                           \
            a_s[BUFI][c4 * 4 + u][r0 + 32] = _t1[u];                           \
            b_s[BUFI][c4 * 4 + u][r0]      = _t2[u];                           \
            b_s[BUFI][c4 * 4 + u][r0 + 32] = _t3[u];                           \
        } } while (0)

    // prologue: stage tile 0
    {
        float4 a0 = x4[(size_t)r0 * H4 + c4];
        float4 a1 = x4[(size_t)(r0 + 32) * H4 + c4];
        float4 b0 = g4[(size_t)r0 * H4 + c4];
        float4 b1 = g4[(size_t)(r0 + 32) * H4 + c4];
        STORE_TILE(0, a0, a1, b0, b1);
    }
    __syncthreads();

    int buf = 0;
    for (int it = 0; it < NITER; ++it) {
        // register-double-buffer: issue next tile's global loads, they retire
        // behind ~1024 cycles of FMA work below.
        float4 na0, na1, nb0, nb1;
        const bool has_next = (it + 1 < NITER);
        if (has_next) {
            const int k4 = (it + 1) * (BK / 4);
            na0 = x4[(size_t)r0 * H4 + k4 + c4];
            na1 = x4[(size_t)(r0 + 32) * H4 + k4 + c4];
            nb0 = g4[(size_t)r0 * H4 + k4 + c4];
            nb1 = g4[(size_t)(r0 + 32) * H4 + k4 + c4];
        }

        #pragma unroll
        for (int kk = 0; kk < BK; ++kk) {
            const float4 afv = *reinterpret_cast<const float4*>(&a_s[buf][kk][ty * 4]);
            const float4 bfv = *reinterpret_cast<const float4*>(&b_s[buf][kk][tx * 4]);
            const float af[4] = {afv.x, afv.y, afv.z, afv.w};
            const float bf[4] = {bfv.x, bfv.y, bfv.z, bfv.w};
            #pragma unroll
            for (int i = 0; i < 4; ++i)
                #pragma unroll
                for (int j = 0; j < 4; ++j)
                    acc[i][j] = fmaf(af[i], bf[j], acc[i][j]);
        }

        if (has_next) STORE_TILE(buf ^ 1, na0, na1, nb0, nb1);
        __syncthreads();
        buf ^= 1;
    }
#undef STORE_TILE

    // scores (+bias) -> LDS
    #pragma unroll
    for (int i = 0; i < 4; ++i)
        #pragma unroll
        for (int j = 0; j < 4; ++j)
            sc_s[ty * 4 + i][tx * 4 + j] = acc[i][j] + bias_s[tx * 4 + j];
    __syncthreads();

    // pass 1: per-token top-2 (jax tie-break: strict '>' keeps lowest index),
    // softmax normalizer, routing-weight + index outputs.
    if (tid < BM) {
        const int t = tid;
        float m1 = -INFINITY, m2 = -INFINITY;
        int   i1 = 0, i2 = 0;
        for (int e = 0; e < NEXP; ++e) {
            const float s = sc_s[t][e];
            if (s > m1)      { m2 = m1; i2 = i1; m1 = s; i1 = e; }
            else if (s > m2) { m2 = s; i2 = e; }
        }
        float z = 0.0f;
        for (int e = 0; e < NEXP; ++e) z += expf(sc_s[t][e] - m1);

        const float e2  = expf(m2 - m1);
        const float inv = 1.0f / (1.0f + e2);
        const int   gt  = t0 + t;
        reinterpret_cast<float2*>(out_w)[gt]   = make_float2(inv, e2 * inv);
        reinterpret_cast<float2*>(out_idx)[gt] = make_float2((float)i1, (float)i2);
        m_s[t] = m1; z_s[t] = z; i1_s[t] = i1; i2_s[t] = i2;
    }
    __syncthreads();

    // pass 2: per-expert partial sums for aux loss (transposed read: lane=expert)
    if (tid < NEXP) {
        const int e = tid;
        float ps = 0.0f, gs = 0.0f;
        for (int t = 0; t < BM; ++t) {
            ps += expf(sc_s[t][e] - m_s[t]) / z_s[t];
            gs += (float)((i1_s[t] == e) + (i2_s[t] == e));
        }
        atomicAdd(&prob_acc[e], ps);
        atomicAdd(&gate_acc[e], gs);
    }
}

// ---------------------------------------------------------------------------
// Final aux-loss reduction: aux = E * sum_e (gate_sum[e]/T) * (prob_sum[e]/T)
// ---------------------------------------------------------------------------
__global__ void router_aux(const float* __restrict__ prob_acc,
                           const float* __restrict__ gate_acc,
                           float* __restrict__ out_aux)
{
    const float invT = 1.0f / (float)TTOT;
    const int e = threadIdx.x;  // 64 threads = 1 wave
    float v = (gate_acc[e] * invT) * (prob_acc[e] * invT);
    #pragma unroll
    for (int off = 32; off > 0; off >>= 1)
        v += __shfl_down(v, off);
    if (e == 0) out_aux[0] = v * (float)NEXP;
}

extern "C" void kernel_launch(void* const* d_in, const int* in_sizes, int n_in,
                              void* d_out, int out_size, void* d_ws, size_t ws_size,
                              hipStream_t stream)
{
    const float* x      = (const float*)d_in[0];
    const float* gw     = (const float*)d_in[1];
    const float* rep    = (const float*)d_in[2];
    const float* loads  = (const float*)d_in[3];
    const float* counts = (const float*)d_in[4];
    const int*   total  = (const int*)d_in[5];

    float* out     = (float*)d_out;
    float* out_w   = out;            // [16384*2] routing weights
    float* out_idx = out + 32768;    // [16384*2] expert indices as float
    float* out_aux = out + 65536;    // [1] aux loss

    float* prob_acc = (float*)d_ws;
    float* gate_acc = prob_acc + NEXP;

    hipMemsetAsync(d_ws, 0, 2 * NEXP * sizeof(float), stream);
    router_main<<<dim3(TTOT / BM), dim3(256), 0, stream>>>(
        x, gw, rep, loads, counts, total, out_w, out_idx, prob_acc, gate_acc);
    router_aux<<<dim3(1), dim3(64), 0, stream>>>(prob_acc, gate_acc, out_aux);
}